// Round 1
// baseline (112.935 us; speedup 1.0000x reference)
//
#include <hip/hip_runtime.h>

// WarpV2: out[b,y,x,c] = bilinear(img[b], y + flo[b,y,x,1], x + flo[b,y,x,0])
// TFA dense_image_warp semantics: floor clipped to [0, size-2], alpha to [0,1].
// img [8,256,512,64] f32, flo [8,256,512,2] f32, out [8,256,512,64] f32.

constexpr int B = 8;
constexpr int H = 256;
constexpr int W = 512;
constexpr int C = 64;          // 16 float4 per pixel

__global__ __launch_bounds__(256) void warp_kernel(
    const float4* __restrict__ img4,
    const float2* __restrict__ flo2,
    float4* __restrict__ out4)
{
    int idx = blockIdx.x * blockDim.x + threadIdx.x;   // float4 index
    int c4  = idx & 15;          // which float4 within the 64-channel row
    int p   = idx >> 4;          // pixel index  ((b*H + y)*W + x)
    int x   = p & (W - 1);
    int y   = (p >> 9) & (H - 1);
    int b   = p >> 17;

    float2 f = flo2[p];          // f.x = flo[...,0], f.y = flo[...,1]
    float qx = (float)x + f.x;   // query col
    float qy = (float)y + f.y;   // query row

    float fx = floorf(qx); fx = fminf(fmaxf(fx, 0.0f), (float)(W - 2));
    float fy = floorf(qy); fy = fminf(fmaxf(fy, 0.0f), (float)(H - 2));
    float ax = fminf(fmaxf(qx - fx, 0.0f), 1.0f);
    float ay = fminf(fmaxf(qy - fy, 0.0f), 1.0f);
    int ix = (int)fx;
    int iy = (int)fy;

    int base = (((b * H + iy) * W + ix) << 4) + c4;    // float4 units
    const int rowstep = W << 4;

    float4 tl = img4[base];
    float4 tr = img4[base + 16];
    float4 bl = img4[base + rowstep];
    float4 br = img4[base + rowstep + 16];

    float4 r;
    {
        float t = tl.x + ax * (tr.x - tl.x);
        float u = bl.x + ax * (br.x - bl.x);
        r.x = t + ay * (u - t);
    }
    {
        float t = tl.y + ax * (tr.y - tl.y);
        float u = bl.y + ax * (br.y - bl.y);
        r.y = t + ay * (u - t);
    }
    {
        float t = tl.z + ax * (tr.z - tl.z);
        float u = bl.z + ax * (br.z - bl.z);
        r.z = t + ay * (u - t);
    }
    {
        float t = tl.w + ax * (tr.w - tl.w);
        float u = bl.w + ax * (br.w - bl.w);
        r.w = t + ay * (u - t);
    }
    out4[idx] = r;
}

extern "C" void kernel_launch(void* const* d_in, const int* in_sizes, int n_in,
                              void* d_out, int out_size, void* d_ws, size_t ws_size,
                              hipStream_t stream)
{
    const float4* img4 = (const float4*)d_in[0];
    const float2* flo2 = (const float2*)d_in[1];
    float4*       out4 = (float4*)d_out;

    const int total4 = B * H * W * (C / 4);            // 16,777,216 threads
    dim3 block(256);
    dim3 grid(total4 / 256);
    warp_kernel<<<grid, block, 0, stream>>>(img4, flo2, out4);
}

// Round 3
// 105.437 us; speedup vs baseline: 1.0711x; 1.0711x over previous
//
#include <hip/hip_runtime.h>

// WarpV2: out[b,y,x,c] = bilinear(img[b], y + flo[b,y,x,1], x + flo[b,y,x,0])
// TFA dense_image_warp semantics: floor clipped to [0, size-2], alpha to [0,1].
// img [8,256,512,64] f32, flo [8,256,512,2] f32, out [8,256,512,64] f32.
//
// R2: same as R1 but nontemporal stores go through a native clang vector type
// (ext_vector_type) — __builtin_nontemporal_store rejects HIP_vector_type.

constexpr int B = 8;
constexpr int H = 256;
constexpr int W = 512;
constexpr int C = 64;          // 16 float4 per pixel

typedef float nt_f4 __attribute__((ext_vector_type(4)));

__device__ __forceinline__ nt_f4 bilerp(float4 tl, float4 tr, float4 bl, float4 br,
                                        float ax, float ay)
{
    nt_f4 r;
    {
        float t = tl.x + ax * (tr.x - tl.x);
        float u = bl.x + ax * (br.x - bl.x);
        r.x = t + ay * (u - t);
    }
    {
        float t = tl.y + ax * (tr.y - tl.y);
        float u = bl.y + ax * (br.y - bl.y);
        r.y = t + ay * (u - t);
    }
    {
        float t = tl.z + ax * (tr.z - tl.z);
        float u = bl.z + ax * (br.z - bl.z);
        r.z = t + ay * (u - t);
    }
    {
        float t = tl.w + ax * (tr.w - tl.w);
        float u = bl.w + ax * (br.w - bl.w);
        r.w = t + ay * (u - t);
    }
    return r;
}

__global__ __launch_bounds__(256) void warp_kernel(
    const float4* __restrict__ img4,
    const float2* __restrict__ flo2,
    nt_f4* __restrict__ out4)
{
    int idx = blockIdx.x * blockDim.x + threadIdx.x;   // half-pixel-row index
    int c4  = idx & 7;           // this thread covers float4 chunks c4 and c4+8
    int p   = idx >> 3;          // pixel index  ((b*H + y)*W + x)
    int x   = p & (W - 1);
    int y   = (p >> 9) & (H - 1);
    int b   = p >> 17;

    float2 f = flo2[p];          // f.x = flo[...,0] (dx), f.y = flo[...,1] (dy)
    float qx = (float)x + f.x;
    float qy = (float)y + f.y;

    float fx = floorf(qx); fx = fminf(fmaxf(fx, 0.0f), (float)(W - 2));
    float fy = floorf(qy); fy = fminf(fmaxf(fy, 0.0f), (float)(H - 2));
    float ax = fminf(fmaxf(qx - fx, 0.0f), 1.0f);
    float ay = fminf(fmaxf(qy - fy, 0.0f), 1.0f);
    int ix = (int)fx;
    int iy = (int)fy;

    int base = (((b * H + iy) * W + ix) << 4) + c4;    // float4 units
    const int rowstep = W << 4;

    // 8 independent gathers -> deep MLP per wave
    float4 tl0 = img4[base];
    float4 tr0 = img4[base + 16];
    float4 bl0 = img4[base + rowstep];
    float4 br0 = img4[base + rowstep + 16];
    float4 tl1 = img4[base + 8];
    float4 tr1 = img4[base + 24];
    float4 bl1 = img4[base + rowstep + 8];
    float4 br1 = img4[base + rowstep + 24];

    nt_f4 r0 = bilerp(tl0, tr0, bl0, br0, ax, ay);
    nt_f4 r1 = bilerp(tl1, tr1, bl1, br1, ax, ay);

    int o = (p << 4) + c4;
    __builtin_nontemporal_store(r0, &out4[o]);
    __builtin_nontemporal_store(r1, &out4[o + 8]);
}

extern "C" void kernel_launch(void* const* d_in, const int* in_sizes, int n_in,
                              void* d_out, int out_size, void* d_ws, size_t ws_size,
                              hipStream_t stream)
{
    const float4* img4 = (const float4*)d_in[0];
    const float2* flo2 = (const float2*)d_in[1];
    nt_f4*        out4 = (nt_f4*)d_out;

    const int total = B * H * W * (C / 8);             // 8,388,608 threads
    dim3 block(256);
    dim3 grid(total / 256);
    warp_kernel<<<grid, block, 0, stream>>>(img4, flo2, out4);
}

// Round 4
// 92.458 us; speedup vs baseline: 1.2215x; 1.1404x over previous
//
#include <hip/hip_runtime.h>

// WarpV2: out[b,y,x,c] = bilinear(img[b], y + flo[b,y,x,1], x + flo[b,y,x,0])
// TFA dense_image_warp semantics: floor clipped to [0, size-2], alpha to [0,1].
// img [8,256,512,64] f32, flo [8,256,512,2] f32, out [8,256,512,64] f32.
//
// R3: XCD-aware block swizzle — 32768 blocks / 8 XCDs = 4096 blocks per XCD
// = exactly one batch image per XCD. All img gather reuse stays in one XCD's
// L2. flo streamed via nontemporal load (no reuse), out via nontemporal store.

constexpr int B = 8;
constexpr int H = 256;
constexpr int W = 512;
constexpr int C = 64;          // 16 float4 per pixel

typedef float nt_f4 __attribute__((ext_vector_type(4)));
typedef float nt_f2 __attribute__((ext_vector_type(2)));

__device__ __forceinline__ nt_f4 bilerp(float4 tl, float4 tr, float4 bl, float4 br,
                                        float ax, float ay)
{
    nt_f4 r;
    {
        float t = tl.x + ax * (tr.x - tl.x);
        float u = bl.x + ax * (br.x - bl.x);
        r.x = t + ay * (u - t);
    }
    {
        float t = tl.y + ax * (tr.y - tl.y);
        float u = bl.y + ax * (br.y - bl.y);
        r.y = t + ay * (u - t);
    }
    {
        float t = tl.z + ax * (tr.z - tl.z);
        float u = bl.z + ax * (br.z - bl.z);
        r.z = t + ay * (u - t);
    }
    {
        float t = tl.w + ax * (tr.w - tl.w);
        float u = bl.w + ax * (br.w - bl.w);
        r.w = t + ay * (u - t);
    }
    return r;
}

__global__ __launch_bounds__(256) void warp_kernel(
    const float4* __restrict__ img4,
    const nt_f2* __restrict__ flo2,
    nt_f4* __restrict__ out4)
{
    // XCD swizzle: nwg = 32768 (divisible by 8). XCD k (= bid%8) gets the
    // contiguous work range [k*4096, (k+1)*4096) -> exactly batch image k.
    int bid  = blockIdx.x;
    int work = ((bid & 7) << 12) + (bid >> 3);
    int idx  = (work << 8) + threadIdx.x;    // half-pixel-row index

    int c4  = idx & 7;           // this thread covers float4 chunks c4 and c4+8
    int p   = idx >> 3;          // pixel index  ((b*H + y)*W + x)
    int x   = p & (W - 1);
    int y   = (p >> 9) & (H - 1);
    int b   = p >> 17;

    nt_f2 f = __builtin_nontemporal_load(&flo2[p]);  // f.x = dx, f.y = dy
    float qx = (float)x + f.x;
    float qy = (float)y + f.y;

    float fx = floorf(qx); fx = fminf(fmaxf(fx, 0.0f), (float)(W - 2));
    float fy = floorf(qy); fy = fminf(fmaxf(fy, 0.0f), (float)(H - 2));
    float ax = fminf(fmaxf(qx - fx, 0.0f), 1.0f);
    float ay = fminf(fmaxf(qy - fy, 0.0f), 1.0f);
    int ix = (int)fx;
    int iy = (int)fy;

    int base = (((b * H + iy) * W + ix) << 4) + c4;    // float4 units
    const int rowstep = W << 4;

    // 8 independent gathers -> deep MLP per wave
    float4 tl0 = img4[base];
    float4 tr0 = img4[base + 16];
    float4 bl0 = img4[base + rowstep];
    float4 br0 = img4[base + rowstep + 16];
    float4 tl1 = img4[base + 8];
    float4 tr1 = img4[base + 24];
    float4 bl1 = img4[base + rowstep + 8];
    float4 br1 = img4[base + rowstep + 24];

    nt_f4 r0 = bilerp(tl0, tr0, bl0, br0, ax, ay);
    nt_f4 r1 = bilerp(tl1, tr1, bl1, br1, ax, ay);

    int o = (p << 4) + c4;
    __builtin_nontemporal_store(r0, &out4[o]);
    __builtin_nontemporal_store(r1, &out4[o + 8]);
}

extern "C" void kernel_launch(void* const* d_in, const int* in_sizes, int n_in,
                              void* d_out, int out_size, void* d_ws, size_t ws_size,
                              hipStream_t stream)
{
    const float4* img4 = (const float4*)d_in[0];
    const nt_f2*  flo2 = (const nt_f2*)d_in[1];
    nt_f4*        out4 = (nt_f4*)d_out;

    const int total = B * H * W * (C / 8);             // 8,388,608 threads
    dim3 block(256);
    dim3 grid(total / 256);                            // 32768 blocks
    warp_kernel<<<grid, block, 0, stream>>>(img4, flo2, out4);
}